// Round 1
// baseline (5098.870 us; speedup 1.0000x reference)
//
#include <hip/hip_runtime.h>
#include <hip/hip_bf16.h>
#include <cmath>

#define BB 32
#define SS 256
#define DD 1024
#define EE 256
#define FDIM 2048
#define HH 512

static constexpr float SCALE = 1.0f / 32.0f;   // 1/sqrt(1024)
static constexpr float EPSF  = 1e-13f;

__device__ inline float4 ld4(const float* p) { return *(const float4*)p; }

// ---------------- softmax over rows of (B*S, S); mask (B,S) over columns or null ---------
__global__ __launch_bounds__(256)
void softmax_rows_k(const float* __restrict__ in, const int* __restrict__ mask,
                    float* __restrict__ out) {
    __shared__ float  redm[4];
    __shared__ float2 reds[4];
    const int row = blockIdx.x;          // 0..B*S-1
    const int b   = row >> 8;
    const int j   = threadIdx.x;         // 0..255
    const float v = in[(size_t)row * SS + j];
    float mj = 1.0f, z = v;
    if (mask) { mj = (float)mask[b * SS + j]; z = v * mj; }
    float M = z;
#pragma unroll
    for (int off = 1; off < 64; off <<= 1) M = fmaxf(M, __shfl_xor(M, off));
    const int wid = j >> 6;
    if ((j & 63) == 0) redm[wid] = M;
    __syncthreads();
    M = fmaxf(fmaxf(redm[0], redm[1]), fmaxf(redm[2], redm[3]));
    const float e = expf(z - M);
    const float r = e * mj;
    float sz = e, sr = r;
#pragma unroll
    for (int off = 1; off < 64; off <<= 1) {
        sz += __shfl_xor(sz, off);
        sr += __shfl_xor(sr, off);
    }
    if ((j & 63) == 0) reds[wid] = make_float2(sz, sr);
    __syncthreads();
    const float Z  = reds[0].x + reds[1].x + reds[2].x + reds[3].x;
    const float Sm = reds[0].y + reds[1].y + reds[2].y + reds[3].y;
    const float o  = mask ? (r / (Sm + EPSF * Z)) : (e / Z);
    out[(size_t)row * SS + j] = o;
}

// ---------------- column sums: o[b,j] = sum_i M[b,i,j];  M (B,S,S) ----------------------
__global__ __launch_bounds__(256)
void colsum_k(const float* __restrict__ M, float* __restrict__ o) {
    const int b = blockIdx.x;
    const int j = threadIdx.x;
    const float* Mb = M + (size_t)b * SS * SS;
    float s = 0.f;
    for (int i = 0; i < SS; ++i) s += Mb[i * SS + j];
    o[b * SS + j] = s;
}

// ---------------- batched NT GEMM: C[b,i,j] = SCALE * sum_d A[b,i,d]*Bm[b,j,d] ----------
// optionally also writes CT[b,j,i]
template <bool WT>
__global__ __launch_bounds__(256)
void gemm_nt_k(const float* __restrict__ A, const float* __restrict__ Bm,
               float* __restrict__ C, float* __restrict__ CT) {
    __shared__ float As[16][68];
    __shared__ float Bs[16][68];
    const int b    = blockIdx.z;
    const int col0 = blockIdx.x * 64;
    const int row0 = blockIdx.y * 64;
    const float* Ab = A  + (size_t)b * SS * DD;
    const float* Bb = Bm + (size_t)b * SS * DD;
    const int tid = threadIdx.x;
    const int tx = tid & 15, ty = tid >> 4;
    const int lr = tid >> 2, lk = (tid & 3) * 4;
    float acc[4][4] = {};
    for (int k0 = 0; k0 < DD; k0 += 16) {
        const float4 av = ld4(Ab + (size_t)(row0 + lr) * DD + k0 + lk);
        const float4 bv = ld4(Bb + (size_t)(col0 + lr) * DD + k0 + lk);
        __syncthreads();
        As[lk + 0][lr] = av.x; As[lk + 1][lr] = av.y; As[lk + 2][lr] = av.z; As[lk + 3][lr] = av.w;
        Bs[lk + 0][lr] = bv.x; Bs[lk + 1][lr] = bv.y; Bs[lk + 2][lr] = bv.z; Bs[lk + 3][lr] = bv.w;
        __syncthreads();
#pragma unroll
        for (int kk = 0; kk < 16; ++kk) {
            const float4 a4 = *(const float4*)&As[kk][ty * 4];
            const float4 b4 = *(const float4*)&Bs[kk][tx * 4];
            const float a[4] = {a4.x, a4.y, a4.z, a4.w};
            const float bb2[4] = {b4.x, b4.y, b4.z, b4.w};
#pragma unroll
            for (int i = 0; i < 4; ++i)
#pragma unroll
                for (int j = 0; j < 4; ++j) acc[i][j] += a[i] * bb2[j];
        }
    }
    float* Cb = C + (size_t)b * SS * SS;
#pragma unroll
    for (int i = 0; i < 4; ++i) {
        const int r = row0 + ty * 4 + i;
        *(float4*)(Cb + (size_t)r * SS + col0 + tx * 4) =
            make_float4(acc[i][0] * SCALE, acc[i][1] * SCALE, acc[i][2] * SCALE, acc[i][3] * SCALE);
    }
    if (WT) {
        float* Tb = CT + (size_t)b * SS * SS;
#pragma unroll
        for (int j = 0; j < 4; ++j) {
            const int c = col0 + tx * 4 + j;
            *(float4*)(Tb + (size_t)c * SS + row0 + ty * 4) =
                make_float4(acc[0][j] * SCALE, acc[1][j] * SCALE, acc[2][j] * SCALE, acc[3][j] * SCALE);
        }
    }
}

// ---------------- batched NN GEMM: C[b,i,d] = (sum_j W[b,i,j] V[b,j,d]) * rowmask[b,i] --
__global__ __launch_bounds__(256)
void gemm_att_k(const float* __restrict__ W, const float* __restrict__ V,
                const int* __restrict__ rowmask, float* __restrict__ C) {
    __shared__ float As[16][68];
    __shared__ float Bs[16][68];
    const int b    = blockIdx.z;
    const int col0 = blockIdx.x * 64;
    const int row0 = blockIdx.y * 64;
    const float* Wb = W + (size_t)b * SS * SS;
    const float* Vb = V + (size_t)b * SS * DD;
    const int tid = threadIdx.x;
    const int tx = tid & 15, ty = tid >> 4;
    const int lr = tid >> 2, lk = (tid & 3) * 4;
    const int bk = tid >> 4, bn = (tid & 15) * 4;
    float acc[4][4] = {};
    for (int k0 = 0; k0 < SS; k0 += 16) {
        const float4 av = ld4(Wb + (size_t)(row0 + lr) * SS + k0 + lk);
        const float4 bv = ld4(Vb + (size_t)(k0 + bk) * DD + col0 + bn);
        __syncthreads();
        As[lk + 0][lr] = av.x; As[lk + 1][lr] = av.y; As[lk + 2][lr] = av.z; As[lk + 3][lr] = av.w;
        *(float4*)&Bs[bk][bn] = bv;
        __syncthreads();
#pragma unroll
        for (int kk = 0; kk < 16; ++kk) {
            const float4 a4 = *(const float4*)&As[kk][ty * 4];
            const float4 b4 = *(const float4*)&Bs[kk][tx * 4];
            const float a[4] = {a4.x, a4.y, a4.z, a4.w};
            const float bb2[4] = {b4.x, b4.y, b4.z, b4.w};
#pragma unroll
            for (int i = 0; i < 4; ++i)
#pragma unroll
                for (int j = 0; j < 4; ++j) acc[i][j] += a[i] * bb2[j];
        }
    }
    float* Cb = C + (size_t)b * SS * DD;
#pragma unroll
    for (int i = 0; i < 4; ++i) {
        const int r = row0 + ty * 4 + i;
        const float mm = rowmask ? (float)rowmask[b * SS + r] : 1.0f;
        *(float4*)(Cb + (size_t)r * DD + col0 + tx * 4) =
            make_float4(acc[i][0] * mm, acc[i][1] * mm, acc[i][2] * mm, acc[i][3] * mm);
    }
}

// ---------------- fuse: cat[row, kf*256+e] = B8[kf,e] + sum_d featkf(x,s,i)[d]*W8[kf,d,e]
__global__ __launch_bounds__(256)
void gemm_fuse_k(const float* __restrict__ X, const float* __restrict__ impS,
                 const float* __restrict__ impI, const float* __restrict__ W8,
                 const float* __restrict__ B8v, float* __restrict__ cat) {
    __shared__ float As[16][68];
    __shared__ float Bs[16][68];
    const int kf   = blockIdx.x >> 2;
    const int e0   = (blockIdx.x & 3) * 64;
    const int row0 = blockIdx.y * 64;
    const int tid = threadIdx.x;
    const int tx = tid & 15, ty = tid >> 4;
    const int lr = tid >> 2, lk = (tid & 3) * 4;
    const int bk = tid >> 4, bn = (tid & 15) * 4;
    const float s_ = impS[row0 + lr];
    const float i_ = impI[row0 + lr];
    float coef = 0.f; int mode = 0;
    switch (kf) {
        case 0: coef = s_ * i_;              break;
        case 1: coef = s_ + i_;              break;
        case 2: coef = fmaxf(s_, i_);        break;
        case 3: mode = 1;                    break;
        case 4: coef = s_ * i_ + 1.f;        break;
        case 5: coef = s_ + i_ + 1.f;        break;
        case 6: coef = fmaxf(s_, i_) + 1.f;  break;
        default: mode = 2;                   break;
    }
    const float* W8k = W8 + (size_t)kf * DD * EE;
    float acc[4][4] = {};
    for (int k0 = 0; k0 < DD; k0 += 16) {
        const float4 av = ld4(X + (size_t)(row0 + lr) * DD + k0 + lk);
        const float4 bv = ld4(W8k + (size_t)(k0 + bk) * EE + e0 + bn);
        float a0, a1, a2, a3;
        if (mode == 0) { a0 = av.x * coef; a1 = av.y * coef; a2 = av.z * coef; a3 = av.w * coef; }
        else if (mode == 1) {
            a0 = fmaxf(av.x * s_, av.x * i_); a1 = fmaxf(av.y * s_, av.y * i_);
            a2 = fmaxf(av.z * s_, av.z * i_); a3 = fmaxf(av.w * s_, av.w * i_);
        } else {
            a0 = fmaxf(av.x * s_, av.x * i_) + av.x; a1 = fmaxf(av.y * s_, av.y * i_) + av.y;
            a2 = fmaxf(av.z * s_, av.z * i_) + av.z; a3 = fmaxf(av.w * s_, av.w * i_) + av.w;
        }
        __syncthreads();
        As[lk + 0][lr] = a0; As[lk + 1][lr] = a1; As[lk + 2][lr] = a2; As[lk + 3][lr] = a3;
        *(float4*)&Bs[bk][bn] = bv;
        __syncthreads();
#pragma unroll
        for (int kk = 0; kk < 16; ++kk) {
            const float4 a4 = *(const float4*)&As[kk][ty * 4];
            const float4 b4 = *(const float4*)&Bs[kk][tx * 4];
            const float a[4] = {a4.x, a4.y, a4.z, a4.w};
            const float bb2[4] = {b4.x, b4.y, b4.z, b4.w};
#pragma unroll
            for (int i = 0; i < 4; ++i)
#pragma unroll
                for (int j = 0; j < 4; ++j) acc[i][j] += a[i] * bb2[j];
        }
    }
#pragma unroll
    for (int i = 0; i < 4; ++i) {
        const int r = row0 + ty * 4 + i;
        const int c = e0 + tx * 4;
        *(float4*)(cat + (size_t)r * FDIM + kf * EE + c) =
            make_float4(acc[i][0] + B8v[kf * EE + c + 0], acc[i][1] + B8v[kf * EE + c + 1],
                        acc[i][2] + B8v[kf * EE + c + 2], acc[i][3] + B8v[kf * EE + c + 3]);
    }
}

// ---------------- lin: C = relu(A(8192,2048) @ Bw(2048,2048) + bias) --------------------
__global__ __launch_bounds__(256)
void gemm_lin_k(const float* __restrict__ A, const float* __restrict__ Bw,
                const float* __restrict__ bias, float* __restrict__ C) {
    __shared__ float As[16][68];
    __shared__ float Bs[16][68];
    const int col0 = blockIdx.x * 64;
    const int row0 = blockIdx.y * 64;
    const int tid = threadIdx.x;
    const int tx = tid & 15, ty = tid >> 4;
    const int lr = tid >> 2, lk = (tid & 3) * 4;
    const int bk = tid >> 4, bn = (tid & 15) * 4;
    float acc[4][4] = {};
    for (int k0 = 0; k0 < FDIM; k0 += 16) {
        const float4 av = ld4(A  + (size_t)(row0 + lr) * FDIM + k0 + lk);
        const float4 bv = ld4(Bw + (size_t)(k0 + bk) * FDIM + col0 + bn);
        __syncthreads();
        As[lk + 0][lr] = av.x; As[lk + 1][lr] = av.y; As[lk + 2][lr] = av.z; As[lk + 3][lr] = av.w;
        *(float4*)&Bs[bk][bn] = bv;
        __syncthreads();
#pragma unroll
        for (int kk = 0; kk < 16; ++kk) {
            const float4 a4 = *(const float4*)&As[kk][ty * 4];
            const float4 b4 = *(const float4*)&Bs[kk][tx * 4];
            const float a[4] = {a4.x, a4.y, a4.z, a4.w};
            const float bb2[4] = {b4.x, b4.y, b4.z, b4.w};
#pragma unroll
            for (int i = 0; i < 4; ++i)
#pragma unroll
                for (int j = 0; j < 4; ++j) acc[i][j] += a[i] * bb2[j];
        }
    }
#pragma unroll
    for (int i = 0; i < 4; ++i) {
        const int r = row0 + ty * 4 + i;
        const int c = col0 + tx * 4;
        *(float4*)(C + (size_t)r * FDIM + c) =
            make_float4(fmaxf(acc[i][0] + bias[c + 0], 0.f), fmaxf(acc[i][1] + bias[c + 1], 0.f),
                        fmaxf(acc[i][2] + bias[c + 2], 0.f), fmaxf(acc[i][3] + bias[c + 3], 0.f));
    }
}

// ---------------- out: relu(enh(8192,7168) @ Wp(7168,512) + bp); enh assembled on the fly
__device__ inline float4 enh4(const float* __restrict__ X, const float* __restrict__ att,
                              const float* __restrict__ sel, const float* __restrict__ pall,
                              int row, int k) {
    if (k < DD)        return ld4(X   + (size_t)row * DD + k);
    if (k < 2 * DD)    return ld4(att + (size_t)row * DD + (k - DD));
    if (k < 3 * DD)    return ld4(sel + (size_t)row * DD + (k - 2 * DD));
    if (k < 3 * DD + FDIM) return ld4(pall + (size_t)row * FDIM + (k - 3 * DD));
    if (k < 3 * DD + FDIM + DD) {
        const int d = k - (3 * DD + FDIM);
        const float4 a = ld4(X + (size_t)row * DD + d), t = ld4(att + (size_t)row * DD + d);
        return make_float4(a.x * t.x, a.y * t.y, a.z * t.z, a.w * t.w);
    }
    const int d = k - (3 * DD + FDIM + DD);
    const float4 a = ld4(X + (size_t)row * DD + d), t = ld4(att + (size_t)row * DD + d);
    return make_float4(a.x - t.x, a.y - t.y, a.z - t.z, a.w - t.w);
}

__global__ __launch_bounds__(256)
void gemm_out_k(const float* __restrict__ X, const float* __restrict__ att,
                const float* __restrict__ sel, const float* __restrict__ pall,
                const float* __restrict__ Wp, const float* __restrict__ bp,
                float* __restrict__ out) {
    __shared__ float As[16][68];
    __shared__ float Bs[16][68];
    const int col0 = blockIdx.x * 64;
    const int row0 = blockIdx.y * 64;
    const int tid = threadIdx.x;
    const int tx = tid & 15, ty = tid >> 4;
    const int lr = tid >> 2, lk = (tid & 3) * 4;
    const int bk = tid >> 4, bn = (tid & 15) * 4;
    float acc[4][4] = {};
    for (int k0 = 0; k0 < 7 * DD; k0 += 16) {
        const float4 av = enh4(X, att, sel, pall, row0 + lr, k0 + lk);
        const float4 bv = ld4(Wp + (size_t)(k0 + bk) * HH + col0 + bn);
        __syncthreads();
        As[lk + 0][lr] = av.x; As[lk + 1][lr] = av.y; As[lk + 2][lr] = av.z; As[lk + 3][lr] = av.w;
        *(float4*)&Bs[bk][bn] = bv;
        __syncthreads();
#pragma unroll
        for (int kk = 0; kk < 16; ++kk) {
            const float4 a4 = *(const float4*)&As[kk][ty * 4];
            const float4 b4 = *(const float4*)&Bs[kk][tx * 4];
            const float a[4] = {a4.x, a4.y, a4.z, a4.w};
            const float bb2[4] = {b4.x, b4.y, b4.z, b4.w};
#pragma unroll
            for (int i = 0; i < 4; ++i)
#pragma unroll
                for (int j = 0; j < 4; ++j) acc[i][j] += a[i] * bb2[j];
        }
    }
#pragma unroll
    for (int i = 0; i < 4; ++i) {
        const int r = row0 + ty * 4 + i;
        const int c = col0 + tx * 4;
        *(float4*)(out + (size_t)r * HH + c) =
            make_float4(fmaxf(acc[i][0] + bp[c + 0], 0.f), fmaxf(acc[i][1] + bp[c + 1], 0.f),
                        fmaxf(acc[i][2] + bp[c + 2], 0.f), fmaxf(acc[i][3] + bp[c + 3], 0.f));
    }
}

extern "C" void kernel_launch(void* const* d_in, const int* in_sizes, int n_in,
                              void* d_out, int out_size, void* d_ws, size_t ws_size,
                              hipStream_t stream) {
    const float* P   = (const float*)d_in[0];
    const float* Hb  = (const float*)d_in[1];
    const int*   pma = (const int*)d_in[2];
    const int*   hma = (const int*)d_in[3];
    const float* W8  = (const float*)d_in[4];
    const float* B8v = (const float*)d_in[5];
    const float* Wl  = (const float*)d_in[6];
    const float* bl  = (const float*)d_in[7];
    const float* Wp  = (const float*)d_in[8];
    const float* bp  = (const float*)d_in[9];

    float* ws = (float*)d_ws;
    float* sim   = ws;                       // B*S*S   = 2,097,152
    float* ph    = sim   + (size_t)BB * SS * SS;
    float* hp    = ph    + (size_t)BB * SS * SS;
    float* attn  = hp    + (size_t)BB * SS * SS;   // simT, then sp/sh_attn
    float* att   = attn  + (size_t)BB * SS * SS;   // B*S*D = 8,388,608
    float* selfv = att   + (size_t)BB * SS * DD;
    float* cat   = selfv + (size_t)BB * SS * DD;   // B*S*2048
    float* lin   = cat   + (size_t)BB * SS * FDIM;
    float* imp_p = lin   + (size_t)BB * SS * FDIM; // B*S each
    float* imp_h = imp_p + (size_t)BB * SS;
    float* iimp_p = imp_h + (size_t)BB * SS;
    float* iimp_h = iimp_p + (size_t)BB * SS;

    float* out_p = (float*)d_out;
    float* out_h = out_p + (size_t)BB * SS * HH;

    const dim3 blk(256);
    const dim3 g_nt(4, 4, BB);
    const dim3 g_att(DD / 64, SS / 64, BB);
    const dim3 g_fuse(32, (BB * SS) / 64);
    const dim3 g_lin(FDIM / 64, (BB * SS) / 64);
    const dim3 g_out(HH / 64, (BB * SS) / 64);

    // sim = scale * P@H^T (+ transposed copy into attn)
    gemm_nt_k<true><<<g_nt, blk, 0, stream>>>(P, Hb, sim, attn);
    // ph = masked_softmax(sim, hm); hp = masked_softmax(sim^T, pm)
    softmax_rows_k<<<BB * SS, blk, 0, stream>>>(sim, hma, ph);
    softmax_rows_k<<<BB * SS, blk, 0, stream>>>(attn, pma, hp);
    colsum_k<<<BB, blk, 0, stream>>>(ph, iimp_h);   // inter_imp_h
    colsum_k<<<BB, blk, 0, stream>>>(hp, iimp_p);   // inter_imp_p

    // ---------------- premise side ----------------
    gemm_nt_k<false><<<g_nt, blk, 0, stream>>>(P, P, sim, nullptr);
    softmax_rows_k<<<BB * SS, blk, 0, stream>>>(sim, nullptr, attn);   // sp_attn
    colsum_k<<<BB, blk, 0, stream>>>(attn, imp_p);
    gemm_att_k<<<g_att, blk, 0, stream>>>(attn, P, nullptr, selfv);    // self_p
    gemm_att_k<<<g_att, blk, 0, stream>>>(ph, Hb, pma, att);           // att_p
    gemm_fuse_k<<<g_fuse, blk, 0, stream>>>(P, imp_p, iimp_p, W8, B8v, cat);
    gemm_lin_k<<<g_lin, blk, 0, stream>>>(cat, Wl, bl, lin);
    gemm_out_k<<<g_out, blk, 0, stream>>>(P, att, selfv, lin, Wp, bp, out_p);

    // ---------------- hypothesis side ----------------
    gemm_nt_k<false><<<g_nt, blk, 0, stream>>>(Hb, Hb, sim, nullptr);
    softmax_rows_k<<<BB * SS, blk, 0, stream>>>(sim, nullptr, attn);   // sh_attn
    colsum_k<<<BB, blk, 0, stream>>>(attn, imp_h);
    gemm_att_k<<<g_att, blk, 0, stream>>>(attn, Hb, nullptr, selfv);   // self_h
    gemm_att_k<<<g_att, blk, 0, stream>>>(hp, P, hma, att);            // att_h
    gemm_fuse_k<<<g_fuse, blk, 0, stream>>>(Hb, imp_h, iimp_h, W8, B8v, cat);
    gemm_lin_k<<<g_lin, blk, 0, stream>>>(cat, Wl, bl, lin);
    gemm_out_k<<<g_out, blk, 0, stream>>>(Hb, att, selfv, lin, Wp, bp, out_h);

    (void)in_sizes; (void)n_in; (void)out_size; (void)ws_size;
}

// Round 2
// 1529.922 us; speedup vs baseline: 3.3328x; 3.3328x over previous
//
#include <hip/hip_runtime.h>
#include <hip/hip_bf16.h>
#include <cmath>

#define BB 32
#define SS 256
#define DD 1024
#define EE 256
#define FDIM 2048
#define HH 512

static constexpr float SCALE = 1.0f / 32.0f;   // 1/sqrt(1024)
static constexpr float EPSF  = 1e-13f;

typedef __attribute__((ext_vector_type(8))) short bf16x8;
typedef __attribute__((ext_vector_type(4))) float f32x4;

__device__ inline float4 ld4(const float* p) { return *(const float4*)p; }
__device__ inline ushort f2b(float f) {
    uint x = __float_as_uint(f);
    x += 0x7fffu + ((x >> 16) & 1u);      // round-to-nearest-even
    return (ushort)(x >> 16);
}
__device__ inline bf16x8 cvt8(const float* v) {
    bf16x8 r;
#pragma unroll
    for (int j = 0; j < 8; ++j) r[j] = (short)f2b(v[j]);
    return r;
}

// =========================== f32 helper kernels (unchanged) ===========================
__global__ __launch_bounds__(256)
void softmax_rows_k(const float* __restrict__ in, const int* __restrict__ mask,
                    float* __restrict__ out) {
    __shared__ float  redm[4];
    __shared__ float2 reds[4];
    const int row = blockIdx.x;
    const int b   = row >> 8;
    const int j   = threadIdx.x;
    const float v = in[(size_t)row * SS + j];
    float mj = 1.0f, z = v;
    if (mask) { mj = (float)mask[b * SS + j]; z = v * mj; }
    float M = z;
#pragma unroll
    for (int off = 1; off < 64; off <<= 1) M = fmaxf(M, __shfl_xor(M, off));
    const int wid = j >> 6;
    if ((j & 63) == 0) redm[wid] = M;
    __syncthreads();
    M = fmaxf(fmaxf(redm[0], redm[1]), fmaxf(redm[2], redm[3]));
    const float e = expf(z - M);
    const float r = e * mj;
    float sz = e, sr = r;
#pragma unroll
    for (int off = 1; off < 64; off <<= 1) {
        sz += __shfl_xor(sz, off);
        sr += __shfl_xor(sr, off);
    }
    if ((j & 63) == 0) reds[wid] = make_float2(sz, sr);
    __syncthreads();
    const float Z  = reds[0].x + reds[1].x + reds[2].x + reds[3].x;
    const float Sm = reds[0].y + reds[1].y + reds[2].y + reds[3].y;
    const float o  = mask ? (r / (Sm + EPSF * Z)) : (e / Z);
    out[(size_t)row * SS + j] = o;
}

__global__ __launch_bounds__(256)
void colsum_k(const float* __restrict__ M, float* __restrict__ o) {
    const int b = blockIdx.x;
    const int j = threadIdx.x;
    const float* Mb = M + (size_t)b * SS * SS;
    float s = 0.f;
    for (int i = 0; i < SS; ++i) s += Mb[i * SS + j];
    o[b * SS + j] = s;
}

template <bool WT>
__global__ __launch_bounds__(256)
void gemm_nt_k(const float* __restrict__ A, const float* __restrict__ Bm,
               float* __restrict__ C, float* __restrict__ CT) {
    __shared__ float As[16][68];
    __shared__ float Bs[16][68];
    const int b    = blockIdx.z;
    const int col0 = blockIdx.x * 64;
    const int row0 = blockIdx.y * 64;
    const float* Ab = A  + (size_t)b * SS * DD;
    const float* Bb = Bm + (size_t)b * SS * DD;
    const int tid = threadIdx.x;
    const int tx = tid & 15, ty = tid >> 4;
    const int lr = tid >> 2, lk = (tid & 3) * 4;
    float acc[4][4] = {};
    for (int k0 = 0; k0 < DD; k0 += 16) {
        const float4 av = ld4(Ab + (size_t)(row0 + lr) * DD + k0 + lk);
        const float4 bv = ld4(Bb + (size_t)(col0 + lr) * DD + k0 + lk);
        __syncthreads();
        As[lk + 0][lr] = av.x; As[lk + 1][lr] = av.y; As[lk + 2][lr] = av.z; As[lk + 3][lr] = av.w;
        Bs[lk + 0][lr] = bv.x; Bs[lk + 1][lr] = bv.y; Bs[lk + 2][lr] = bv.z; Bs[lk + 3][lr] = bv.w;
        __syncthreads();
#pragma unroll
        for (int kk = 0; kk < 16; ++kk) {
            const float4 a4 = *(const float4*)&As[kk][ty * 4];
            const float4 b4 = *(const float4*)&Bs[kk][tx * 4];
            const float a[4] = {a4.x, a4.y, a4.z, a4.w};
            const float bb2[4] = {b4.x, b4.y, b4.z, b4.w};
#pragma unroll
            for (int i = 0; i < 4; ++i)
#pragma unroll
                for (int j = 0; j < 4; ++j) acc[i][j] += a[i] * bb2[j];
        }
    }
    float* Cb = C + (size_t)b * SS * SS;
#pragma unroll
    for (int i = 0; i < 4; ++i) {
        const int r = row0 + ty * 4 + i;
        *(float4*)(Cb + (size_t)r * SS + col0 + tx * 4) =
            make_float4(acc[i][0] * SCALE, acc[i][1] * SCALE, acc[i][2] * SCALE, acc[i][3] * SCALE);
    }
    if (WT) {
        float* Tb = CT + (size_t)b * SS * SS;
#pragma unroll
        for (int j = 0; j < 4; ++j) {
            const int c = col0 + tx * 4 + j;
            *(float4*)(Tb + (size_t)c * SS + row0 + ty * 4) =
                make_float4(acc[0][j] * SCALE, acc[1][j] * SCALE, acc[2][j] * SCALE, acc[3][j] * SCALE);
        }
    }
}

__global__ __launch_bounds__(256)
void gemm_att_k(const float* __restrict__ W, const float* __restrict__ V,
                const int* __restrict__ rowmask, float* __restrict__ C) {
    __shared__ float As[16][68];
    __shared__ float Bs[16][68];
    const int b    = blockIdx.z;
    const int col0 = blockIdx.x * 64;
    const int row0 = blockIdx.y * 64;
    const float* Wb = W + (size_t)b * SS * SS;
    const float* Vb = V + (size_t)b * SS * DD;
    const int tid = threadIdx.x;
    const int tx = tid & 15, ty = tid >> 4;
    const int lr = tid >> 2, lk = (tid & 3) * 4;
    const int bk = tid >> 4, bn = (tid & 15) * 4;
    float acc[4][4] = {};
    for (int k0 = 0; k0 < SS; k0 += 16) {
        const float4 av = ld4(Wb + (size_t)(row0 + lr) * SS + k0 + lk);
        const float4 bv = ld4(Vb + (size_t)(k0 + bk) * DD + col0 + bn);
        __syncthreads();
        As[lk + 0][lr] = av.x; As[lk + 1][lr] = av.y; As[lk + 2][lr] = av.z; As[lk + 3][lr] = av.w;
        *(float4*)&Bs[bk][bn] = bv;
        __syncthreads();
#pragma unroll
        for (int kk = 0; kk < 16; ++kk) {
            const float4 a4 = *(const float4*)&As[kk][ty * 4];
            const float4 b4 = *(const float4*)&Bs[kk][tx * 4];
            const float a[4] = {a4.x, a4.y, a4.z, a4.w};
            const float bb2[4] = {b4.x, b4.y, b4.z, b4.w};
#pragma unroll
            for (int i = 0; i < 4; ++i)
#pragma unroll
                for (int j = 0; j < 4; ++j) acc[i][j] += a[i] * bb2[j];
        }
    }
    float* Cb = C + (size_t)b * SS * DD;
#pragma unroll
    for (int i = 0; i < 4; ++i) {
        const int r = row0 + ty * 4 + i;
        const float mm = rowmask ? (float)rowmask[b * SS + r] : 1.0f;
        *(float4*)(Cb + (size_t)r * DD + col0 + tx * 4) =
            make_float4(acc[i][0] * mm, acc[i][1] * mm, acc[i][2] * mm, acc[i][3] * mm);
    }
}

// =========================== prep: transpose + f32->bf16 ===========================
// out[n][k] = bf16(in[k][n]);  in: K x N f32, out: N x K bf16
__global__ __launch_bounds__(256)
void tpose_cvt_k(const float* __restrict__ in, ushort* __restrict__ out,
                 int K, int N, size_t inStride, size_t outStride) {
    __shared__ float T[32][33];
    const float* ib = in  + (size_t)blockIdx.z * inStride;
    ushort*      ob = out + (size_t)blockIdx.z * outStride;
    const int k0 = blockIdx.x * 32, n0 = blockIdx.y * 32;
    const int tx = threadIdx.x & 31, ty = threadIdx.x >> 5;
#pragma unroll
    for (int i = 0; i < 4; ++i) T[ty + 8 * i][tx] = ib[(size_t)(k0 + ty + 8 * i) * N + n0 + tx];
    __syncthreads();
#pragma unroll
    for (int i = 0; i < 4; ++i)
        ob[(size_t)(n0 + ty + 8 * i) * K + k0 + tx] = f2b(T[tx][ty + 8 * i]);
}

// =========================== bf16 MFMA GEMM kernels ===========================
// Common: 128x128 tile, BK=32, 256 threads (4 waves, 2x2 of 64x64), 16x16x32 bf16 MFMA.
// LDS tiles As[128][32], Bs[128][32] (both M/N-major, k contiguous). B operand is
// pre-transposed to N x K so frag reads are identical for A and B.
// A frag: lane holds A[16m + (l&15)][(l>>4)*8 + j]; C/D: col=lane&15, row=(l>>4)*4+reg.

#define MFMA_CORE()                                                                  \
    {                                                                                \
        bf16x8 afr[4], bfr[4];                                                       \
        _Pragma("unroll") for (int m = 0; m < 4; ++m)                                \
            afr[m] = *(const bf16x8*)&As[wr + m * 16 + fr][kb];                      \
        _Pragma("unroll") for (int n = 0; n < 4; ++n)                                \
            bfr[n] = *(const bf16x8*)&Bs[wc + n * 16 + fr][kb];                      \
        _Pragma("unroll") for (int m = 0; m < 4; ++m)                                \
            _Pragma("unroll") for (int n = 0; n < 4; ++n)                            \
                acc[m][n] = __builtin_amdgcn_mfma_f32_16x16x32_bf16(                 \
                    afr[m], bfr[n], acc[m][n], 0, 0, 0);                             \
    }

#define MFMA_PREAMBLE()                                                              \
    const int tid = threadIdx.x;                                                     \
    const int lane = tid & 63;                                                       \
    const int w = tid >> 6;                                                          \
    const int wr = (w >> 1) * 64, wc = (w & 1) * 64;                                 \
    const int fr = lane & 15;                                                        \
    const int kb = (lane >> 4) * 8;                                                  \
    const int rq = (lane >> 4) * 4;                                                  \
    f32x4 acc[4][4] = {};

// ---- fuse: cat[row, kf*256+e] = B8[kf,e] + sum_d feat_kf(row,d) * W8[kf,d,e] (bf16 out)
__global__ __launch_bounds__(256)
void mfma_fuse_k(const float* __restrict__ X, const float* __restrict__ impS,
                 const float* __restrict__ impI, const ushort* __restrict__ W8T,
                 const float* __restrict__ B8v, ushort* __restrict__ catb) {
    __shared__ __align__(16) ushort As[128][32];
    __shared__ __align__(16) ushort Bs[128][32];
    const int kf   = blockIdx.x >> 1;
    const int e0   = (blockIdx.x & 1) * 128;
    const int row0 = blockIdx.y * 128;
    MFMA_PREAMBLE();
    const ushort* Wk = W8T + (size_t)kf * EE * DD;

    int   srow_[2]; float sA[2], iA[2], cf[2];
#pragma unroll
    for (int i = 0; i < 2; ++i) {
        const int cid = tid + i * 256;
        srow_[i] = cid >> 2;
        const int row = row0 + srow_[i];
        const float s_ = impS[row], i_ = impI[row];
        sA[i] = s_; iA[i] = i_;
        float c = 0.f;
        switch (kf) {
            case 0: c = s_ * i_;             break;
            case 1: c = s_ + i_;             break;
            case 2: c = fmaxf(s_, i_);       break;
            case 4: c = s_ * i_ + 1.f;       break;
            case 5: c = s_ + i_ + 1.f;       break;
            case 6: c = fmaxf(s_, i_) + 1.f; break;
            default: break;
        }
        cf[i] = c;
    }

    for (int k0 = 0; k0 < DD; k0 += 32) {
        bf16x8 ar[2], br[2];
#pragma unroll
        for (int i = 0; i < 2; ++i) {
            const int cid = tid + i * 256, skc = (cid & 3) * 8;
            const int row = row0 + srow_[i];
            const float4 u0 = ld4(&X[(size_t)row * DD + k0 + skc]);
            const float4 u1 = ld4(&X[(size_t)row * DD + k0 + skc + 4]);
            float v[8] = {u0.x, u0.y, u0.z, u0.w, u1.x, u1.y, u1.z, u1.w};
            if (kf == 3) {
#pragma unroll
                for (int j = 0; j < 8; ++j) v[j] = fmaxf(v[j] * sA[i], v[j] * iA[i]);
            } else if (kf == 7) {
#pragma unroll
                for (int j = 0; j < 8; ++j) v[j] = fmaxf(v[j] * sA[i], v[j] * iA[i]) + v[j];
            } else {
#pragma unroll
                for (int j = 0; j < 8; ++j) v[j] *= cf[i];
            }
            ar[i] = cvt8(v);
            br[i] = *(const bf16x8*)&Wk[(size_t)(e0 + srow_[i]) * DD + k0 + skc];
        }
        __syncthreads();
#pragma unroll
        for (int i = 0; i < 2; ++i) {
            const int cid = tid + i * 256, skc = (cid & 3) * 8;
            *(bf16x8*)&As[srow_[i]][skc] = ar[i];
            *(bf16x8*)&Bs[srow_[i]][skc] = br[i];
        }
        __syncthreads();
        MFMA_CORE();
    }
#pragma unroll
    for (int m = 0; m < 4; ++m)
#pragma unroll
        for (int n = 0; n < 4; ++n) {
            const int el = e0 + wc + n * 16 + fr;           // 0..255 within this kf
            const float bv = B8v[kf * EE + el];
#pragma unroll
            for (int r = 0; r < 4; ++r) {
                const int rr = row0 + wr + m * 16 + rq + r;
                catb[(size_t)rr * FDIM + kf * EE + el] = f2b(acc[m][n][r] + bv);
            }
        }
}

// ---- lin: pall = relu(cat @ Wl + bl)  (bf16 in, bf16 out)
__global__ __launch_bounds__(256)
void mfma_lin_k(const ushort* __restrict__ A, const ushort* __restrict__ BT,
                const float* __restrict__ bias, ushort* __restrict__ C) {
    __shared__ __align__(16) ushort As[128][32];
    __shared__ __align__(16) ushort Bs[128][32];
    const int col0 = blockIdx.x * 128;
    const int row0 = blockIdx.y * 128;
    MFMA_PREAMBLE();
    for (int k0 = 0; k0 < FDIM; k0 += 32) {
        bf16x8 ar[2], br[2];
#pragma unroll
        for (int i = 0; i < 2; ++i) {
            const int cid = tid + i * 256, srow = cid >> 2, skc = (cid & 3) * 8;
            ar[i] = *(const bf16x8*)&A [(size_t)(row0 + srow) * FDIM + k0 + skc];
            br[i] = *(const bf16x8*)&BT[(size_t)(col0 + srow) * FDIM + k0 + skc];
        }
        __syncthreads();
#pragma unroll
        for (int i = 0; i < 2; ++i) {
            const int cid = tid + i * 256, srow = cid >> 2, skc = (cid & 3) * 8;
            *(bf16x8*)&As[srow][skc] = ar[i];
            *(bf16x8*)&Bs[srow][skc] = br[i];
        }
        __syncthreads();
        MFMA_CORE();
    }
#pragma unroll
    for (int m = 0; m < 4; ++m)
#pragma unroll
        for (int n = 0; n < 4; ++n) {
            const int c = col0 + wc + n * 16 + fr;
            const float bv = bias[c];
#pragma unroll
            for (int r = 0; r < 4; ++r) {
                const int rr = row0 + wr + m * 16 + rq + r;
                C[(size_t)rr * FDIM + c] = f2b(fmaxf(acc[m][n][r] + bv, 0.f));
            }
        }
}

// ---- out: relu(enh @ Wp + bp); enh assembled on the fly (f32 out)
__global__ __launch_bounds__(256)
void mfma_out_k(const float* __restrict__ X, const float* __restrict__ att,
                const float* __restrict__ sel, const ushort* __restrict__ pallb,
                const ushort* __restrict__ WpT, const float* __restrict__ bp,
                float* __restrict__ out) {
    __shared__ __align__(16) ushort As[128][32];
    __shared__ __align__(16) ushort Bs[128][32];
    const int col0 = blockIdx.x * 128;      // < 512
    const int row0 = blockIdx.y * 128;
    MFMA_PREAMBLE();
    for (int k0 = 0; k0 < 7 * DD; k0 += 32) {
        bf16x8 ar[2], br[2];
#pragma unroll
        for (int i = 0; i < 2; ++i) {
            const int cid = tid + i * 256, srow = cid >> 2, skc = (cid & 3) * 8;
            const int row = row0 + srow;
            const int kg  = k0 + skc;
            bf16x8 av;
            if (kg < DD) {                       // x (cvt from f32)
                const float4 u0 = ld4(&X[(size_t)row * DD + kg]);
                const float4 u1 = ld4(&X[(size_t)row * DD + kg + 4]);
                float v[8] = {u0.x, u0.y, u0.z, u0.w, u1.x, u1.y, u1.z, u1.w};
                av = cvt8(v);
            } else if (kg < 2 * DD) {            // att
                const int d = kg - DD;
                const float4 u0 = ld4(&att[(size_t)row * DD + d]);
                const float4 u1 = ld4(&att[(size_t)row * DD + d + 4]);
                float v[8] = {u0.x, u0.y, u0.z, u0.w, u1.x, u1.y, u1.z, u1.w};
                av = cvt8(v);
            } else if (kg < 3 * DD) {            // self
                const int d = kg - 2 * DD;
                const float4 u0 = ld4(&sel[(size_t)row * DD + d]);
                const float4 u1 = ld4(&sel[(size_t)row * DD + d + 4]);
                float v[8] = {u0.x, u0.y, u0.z, u0.w, u1.x, u1.y, u1.z, u1.w};
                av = cvt8(v);
            } else if (kg < 3 * DD + FDIM) {     // pall (already bf16)
                const int d = kg - 3 * DD;
                av = *(const bf16x8*)&pallb[(size_t)row * FDIM + d];
            } else if (kg < 3 * DD + FDIM + DD) { // x * att
                const int d = kg - (3 * DD + FDIM);
                const float4 x0 = ld4(&X[(size_t)row * DD + d]);
                const float4 x1 = ld4(&X[(size_t)row * DD + d + 4]);
                const float4 a0 = ld4(&att[(size_t)row * DD + d]);
                const float4 a1 = ld4(&att[(size_t)row * DD + d + 4]);
                float v[8] = {x0.x * a0.x, x0.y * a0.y, x0.z * a0.z, x0.w * a0.w,
                              x1.x * a1.x, x1.y * a1.y, x1.z * a1.z, x1.w * a1.w};
                av = cvt8(v);
            } else {                              // x - att
                const int d = kg - (3 * DD + FDIM + DD);
                const float4 x0 = ld4(&X[(size_t)row * DD + d]);
                const float4 x1 = ld4(&X[(size_t)row * DD + d + 4]);
                const float4 a0 = ld4(&att[(size_t)row * DD + d]);
                const float4 a1 = ld4(&att[(size_t)row * DD + d + 4]);
                float v[8] = {x0.x - a0.x, x0.y - a0.y, x0.z - a0.z, x0.w - a0.w,
                              x1.x - a1.x, x1.y - a1.y, x1.z - a1.z, x1.w - a1.w};
                av = cvt8(v);
            }
            ar[i] = av;
            br[i] = *(const bf16x8*)&WpT[(size_t)(col0 + srow) * (7 * DD) + kg];
        }
        __syncthreads();
#pragma unroll
        for (int i = 0; i < 2; ++i) {
            const int cid = tid + i * 256, srow = cid >> 2, skc = (cid & 3) * 8;
            *(bf16x8*)&As[srow][skc] = ar[i];
            *(bf16x8*)&Bs[srow][skc] = br[i];
        }
        __syncthreads();
        MFMA_CORE();
    }
#pragma unroll
    for (int m = 0; m < 4; ++m)
#pragma unroll
        for (int n = 0; n < 4; ++n) {
            const int c = col0 + wc + n * 16 + fr;
            const float bv = bp[c];
#pragma unroll
            for (int r = 0; r < 4; ++r) {
                const int rr = row0 + wr + m * 16 + rq + r;
                out[(size_t)rr * HH + c] = fmaxf(acc[m][n][r] + bv, 0.f);
            }
        }
}

// =========================== launcher ===========================
extern "C" void kernel_launch(void* const* d_in, const int* in_sizes, int n_in,
                              void* d_out, int out_size, void* d_ws, size_t ws_size,
                              hipStream_t stream) {
    const float* P   = (const float*)d_in[0];
    const float* Hb  = (const float*)d_in[1];
    const int*   pma = (const int*)d_in[2];
    const int*   hma = (const int*)d_in[3];
    const float* W8  = (const float*)d_in[4];
    const float* B8v = (const float*)d_in[5];
    const float* Wl  = (const float*)d_in[6];
    const float* bl  = (const float*)d_in[7];
    const float* Wp  = (const float*)d_in[8];
    const float* bp  = (const float*)d_in[9];

    char* cur = (char*)d_ws;
    auto alloc_f = [&](size_t n) { float*  p = (float*)cur;  cur += n * 4; return p; };
    auto alloc_u = [&](size_t n) { ushort* p = (ushort*)cur; cur += n * 2; return p; };

    float* sim    = alloc_f((size_t)BB * SS * SS);
    float* ph     = alloc_f((size_t)BB * SS * SS);
    float* hp     = alloc_f((size_t)BB * SS * SS);
    float* attn   = alloc_f((size_t)BB * SS * SS);
    float* att    = alloc_f((size_t)BB * SS * DD);
    float* selfv  = alloc_f((size_t)BB * SS * DD);
    float* imp_p  = alloc_f(BB * SS);
    float* imp_h  = alloc_f(BB * SS);
    float* iimp_p = alloc_f(BB * SS);
    float* iimp_h = alloc_f(BB * SS);
    ushort* catb  = alloc_u((size_t)BB * SS * FDIM);
    ushort* pallb = alloc_u((size_t)BB * SS * FDIM);
    ushort* WlT   = alloc_u((size_t)FDIM * FDIM);
    ushort* WpT   = alloc_u((size_t)HH * 7 * DD);
    ushort* W8T   = alloc_u((size_t)8 * EE * DD);

    float* out_p = (float*)d_out;
    float* out_h = out_p + (size_t)BB * SS * HH;

    const dim3 blk(256);
    const dim3 g_nt(4, 4, BB);
    const dim3 g_att(DD / 64, SS / 64, BB);
    const dim3 g_fuse(16, (BB * SS) / 128);
    const dim3 g_lin(FDIM / 128, (BB * SS) / 128);
    const dim3 g_out(HH / 128, (BB * SS) / 128);

    // ---- prep: bf16 transposed weights
    tpose_cvt_k<<<dim3(FDIM / 32, FDIM / 32, 1), blk, 0, stream>>>(Wl, WlT, FDIM, FDIM, 0, 0);
    tpose_cvt_k<<<dim3(7 * DD / 32, HH / 32, 1), blk, 0, stream>>>(Wp, WpT, 7 * DD, HH, 0, 0);
    tpose_cvt_k<<<dim3(DD / 32, EE / 32, 8), blk, 0, stream>>>(W8, W8T, DD, EE,
                                                               (size_t)DD * EE, (size_t)EE * DD);

    // ---- cross attention
    gemm_nt_k<true><<<g_nt, blk, 0, stream>>>(P, Hb, sim, attn);
    softmax_rows_k<<<BB * SS, blk, 0, stream>>>(sim, hma, ph);
    softmax_rows_k<<<BB * SS, blk, 0, stream>>>(attn, pma, hp);
    colsum_k<<<BB, blk, 0, stream>>>(ph, iimp_h);
    colsum_k<<<BB, blk, 0, stream>>>(hp, iimp_p);

    // ---- premise side
    gemm_nt_k<false><<<g_nt, blk, 0, stream>>>(P, P, sim, nullptr);
    softmax_rows_k<<<BB * SS, blk, 0, stream>>>(sim, nullptr, attn);   // sp_attn
    colsum_k<<<BB, blk, 0, stream>>>(attn, imp_p);
    gemm_att_k<<<g_att, blk, 0, stream>>>(attn, P, nullptr, selfv);    // self_p
    gemm_att_k<<<g_att, blk, 0, stream>>>(ph, Hb, pma, att);           // att_p
    mfma_fuse_k<<<g_fuse, blk, 0, stream>>>(P, imp_p, iimp_p, W8T, B8v, catb);
    mfma_lin_k<<<g_lin, blk, 0, stream>>>(catb, WlT, bl, pallb);
    mfma_out_k<<<g_out, blk, 0, stream>>>(P, att, selfv, pallb, WpT, bp, out_p);

    // ---- hypothesis side
    gemm_nt_k<false><<<g_nt, blk, 0, stream>>>(Hb, Hb, sim, nullptr);
    softmax_rows_k<<<BB * SS, blk, 0, stream>>>(sim, nullptr, attn);   // sh_attn
    colsum_k<<<BB, blk, 0, stream>>>(attn, imp_h);
    gemm_att_k<<<g_att, blk, 0, stream>>>(attn, Hb, nullptr, selfv);   // self_h
    gemm_att_k<<<g_att, blk, 0, stream>>>(hp, P, hma, att);            // att_h
    mfma_fuse_k<<<g_fuse, blk, 0, stream>>>(Hb, imp_h, iimp_h, W8T, B8v, catb);
    mfma_lin_k<<<g_lin, blk, 0, stream>>>(catb, WlT, bl, pallb);
    mfma_out_k<<<g_out, blk, 0, stream>>>(Hb, att, selfv, pallb, WpT, bp, out_h);

    (void)in_sizes; (void)n_in; (void)out_size; (void)ws_size;
}

// Round 4
// 821.527 us; speedup vs baseline: 6.2066x; 1.8623x over previous
//
#include <hip/hip_runtime.h>
#include <hip/hip_bf16.h>
#include <cmath>

#define BB 32
#define SS 256
#define DD 1024
#define EE 256
#define FDIM 2048
#define HH 512
#define KOUT (7 * DD)
#define NROW (BB * SS)          // 8192 rows per side
#define NROW2 (2 * NROW)        // 16384 combined

static constexpr float SCALE = 1.0f / 32.0f;   // 1/sqrt(1024)
static constexpr float EPSF  = 1e-13f;

typedef __attribute__((ext_vector_type(8))) short bf16x8;
typedef __attribute__((ext_vector_type(4))) float f32x4;

__device__ inline float4 ld4(const float* p) { return *(const float4*)p; }
__device__ inline ushort f2b(float f) {
    uint x = __float_as_uint(f);
    x += 0x7fffu + ((x >> 16) & 1u);      // round-to-nearest-even
    return (ushort)(x >> 16);
}
__device__ inline float b2f(ushort u) { return __uint_as_float(((uint)u) << 16); }
__device__ inline bf16x8 cvt8(const float* v) {
    bf16x8 r;
#pragma unroll
    for (int j = 0; j < 8; ++j) r[j] = (short)f2b(v[j]);
    return r;
}
__device__ inline void b2f8(bf16x8 v, float* o) {
#pragma unroll
    for (int j = 0; j < 8; ++j) o[j] = b2f((ushort)v[j]);
}
__device__ inline bf16x8 ldf8(const float* p) {
    const float4 u0 = ld4(p), u1 = ld4(p + 4);
    float v[8] = {u0.x, u0.y, u0.z, u0.w, u1.x, u1.y, u1.z, u1.w};
    return cvt8(v);
}

// XCD-chunked swizzle (grid total must be %8==0)
__device__ inline int swz_orig_2d() {
    const int n   = blockIdx.y * gridDim.x + blockIdx.x;
    const int tot = gridDim.x * gridDim.y;
    return (n & 7) * (tot >> 3) + (n >> 3);
}
__device__ inline int swz_orig_3d() {
    const int n   = (blockIdx.z * gridDim.y + blockIdx.y) * gridDim.x + blockIdx.x;
    const int tot = gridDim.x * gridDim.y * gridDim.z;
    return (n & 7) * (tot >> 3) + (n >> 3);
}

// =========================== prep: transpose + f32->bf16 ===========================
__global__ __launch_bounds__(256)
void tpose_cvt_k(const float* __restrict__ in, ushort* __restrict__ out,
                 int K, int N, size_t inStride, size_t outStride) {
    __shared__ float T[32][33];
    const float* ib = in  + (size_t)blockIdx.z * inStride;
    ushort*      ob = out + (size_t)blockIdx.z * outStride;
    const int k0 = blockIdx.x * 32, n0 = blockIdx.y * 32;
    const int tx = threadIdx.x & 31, ty = threadIdx.x >> 5;
#pragma unroll
    for (int i = 0; i < 4; ++i) T[ty + 8 * i][tx] = ib[(size_t)(k0 + ty + 8 * i) * N + n0 + tx];
    __syncthreads();
#pragma unroll
    for (int i = 0; i < 4; ++i)
        ob[(size_t)(n0 + ty + 8 * i) * K + k0 + tx] = f2b(T[tx][ty + 8 * i]);
}

// =========================== softmax (IN-PLACE on sim buffers) ===========================
__global__ __launch_bounds__(256)
void softmax4_k(float* __restrict__ simPH, float* __restrict__ simPHT,
                float* __restrict__ simPP, float* __restrict__ simHH,
                const int* __restrict__ pma, const int* __restrict__ hma) {
    const int job = blockIdx.y;
    float* buf = job == 0 ? simPH : job == 1 ? simPHT : job == 2 ? simPP : simHH;
    const int* mask = job == 0 ? hma : job == 1 ? pma : nullptr;

    __shared__ float  redm[4];
    __shared__ float2 reds[4];
    const int row = blockIdx.x;
    const int b   = row >> 8;
    const int j   = threadIdx.x;
    const float v = buf[(size_t)row * SS + j];
    float mj = 1.0f, z = v;
    if (mask) { mj = (float)mask[b * SS + j]; z = v * mj; }
    float M = z;
#pragma unroll
    for (int off = 1; off < 64; off <<= 1) M = fmaxf(M, __shfl_xor(M, off));
    const int wid = j >> 6;
    if ((j & 63) == 0) redm[wid] = M;
    __syncthreads();
    M = fmaxf(fmaxf(redm[0], redm[1]), fmaxf(redm[2], redm[3]));
    const float e = expf(z - M);
    const float r = e * mj;
    float sz = e, sr = r;
#pragma unroll
    for (int off = 1; off < 64; off <<= 1) {
        sz += __shfl_xor(sz, off);
        sr += __shfl_xor(sr, off);
    }
    if ((j & 63) == 0) reds[wid] = make_float2(sz, sr);
    __syncthreads();
    const float Z  = reds[0].x + reds[1].x + reds[2].x + reds[3].x;
    const float Sm = reds[0].y + reds[1].y + reds[2].y + reds[3].y;
    buf[(size_t)row * SS + j] = mask ? (r / (Sm + EPSF * Z)) : (e / Z);
}

__global__ __launch_bounds__(256)
void colsum4_k(const float* __restrict__ spA, const float* __restrict__ shA,
               const float* __restrict__ hp, const float* __restrict__ ph,
               float* __restrict__ impS, float* __restrict__ impI) {
    const int job = blockIdx.y, b = blockIdx.x, j = threadIdx.x;
    const float* src = job == 0 ? spA : job == 1 ? shA : job == 2 ? hp : ph;
    float* dst = job == 0 ? impS : job == 1 ? impS + NROW : job == 2 ? impI : impI + NROW;
    const float* Mb = src + (size_t)b * SS * SS;
    float s = 0.f;
    for (int i = 0; i < SS; ++i) s += Mb[i * SS + j];
    dst[b * SS + j] = s;
}

// =========================== MFMA common ===========================
#define MFMA_CORE()                                                                  \
    {                                                                                \
        bf16x8 afr[4], bfr[4];                                                       \
        _Pragma("unroll") for (int m = 0; m < 4; ++m)                                \
            afr[m] = *(const bf16x8*)&As[wr + m * 16 + fr][kb];                      \
        _Pragma("unroll") for (int n = 0; n < 4; ++n)                                \
            bfr[n] = *(const bf16x8*)&Bs[wc + n * 16 + fr][kb];                      \
        _Pragma("unroll") for (int m = 0; m < 4; ++m)                                \
            _Pragma("unroll") for (int n = 0; n < 4; ++n)                            \
                acc[m][n] = __builtin_amdgcn_mfma_f32_16x16x32_bf16(                 \
                    afr[m], bfr[n], acc[m][n], 0, 0, 0);                             \
    }

#define MFMA_PREAMBLE()                                                              \
    const int tid = threadIdx.x;                                                     \
    const int lane = tid & 63;                                                       \
    const int w = tid >> 6;                                                          \
    const int wr = (w >> 1) * 64, wc = (w & 1) * 64;                                 \
    const int fr = lane & 15;                                                        \
    const int kb = (lane >> 4) * 8;                                                  \
    const int rq = (lane >> 4) * 4;                                                  \
    f32x4 acc[4][4] = {};

// ---- sim GEMMs (NT): g0 P@H^T(+T), g1 P@P^T, g2 H@H^T; f32 in, f32 out ----
__global__ __launch_bounds__(256)
void mfma_nt_k(const float* __restrict__ P, const float* __restrict__ H,
               float* __restrict__ simPH, float* __restrict__ simPHT,
               float* __restrict__ simPP, float* __restrict__ simHH) {
    __shared__ __align__(16) ushort As[128][32];
    __shared__ __align__(16) ushort Bs[128][32];
    int orig = swz_orig_3d();                 // grid (2,2,96)
    const int cb = orig & 1; orig >>= 1;
    const int rb = orig & 1; orig >>= 1;
    const int g = orig >> 5, b = orig & 31;
    const float* Au = ((g == 2) ? H : P) + (size_t)b * SS * DD;
    const float* Bu = ((g == 1) ? P : H) + (size_t)b * SS * DD;
    const int col0 = cb * 128, row0 = rb * 128;
    MFMA_PREAMBLE();
    for (int k0 = 0; k0 < DD; k0 += 32) {
        bf16x8 ar[2], br[2];
#pragma unroll
        for (int i = 0; i < 2; ++i) {
            const int cid = tid + i * 256, srow = cid >> 2, skc = (cid & 3) * 8;
            ar[i] = ldf8(&Au[(size_t)(row0 + srow) * DD + k0 + skc]);
            br[i] = ldf8(&Bu[(size_t)(col0 + srow) * DD + k0 + skc]);
        }
        __syncthreads();
#pragma unroll
        for (int i = 0; i < 2; ++i) {
            const int cid = tid + i * 256, srow = cid >> 2, skc = (cid & 3) * 8;
            *(bf16x8*)&As[srow][skc] = ar[i];
            *(bf16x8*)&Bs[srow][skc] = br[i];
        }
        __syncthreads();
        MFMA_CORE();
    }
    float* Cb = (g == 0 ? simPH : g == 1 ? simPP : simHH) + (size_t)b * SS * SS;
#pragma unroll
    for (int m = 0; m < 4; ++m)
#pragma unroll
        for (int n = 0; n < 4; ++n) {
            const int c = col0 + wc + n * 16 + fr;
            const int r0 = row0 + wr + m * 16 + rq;
#pragma unroll
            for (int r = 0; r < 4; ++r) Cb[(size_t)(r0 + r) * SS + c] = acc[m][n][r] * SCALE;
            if (g == 0) {
                float* Tb = simPHT + (size_t)b * SS * SS;
                *(float4*)&Tb[(size_t)c * SS + r0] =
                    make_float4(acc[m][n][0] * SCALE, acc[m][n][1] * SCALE,
                                acc[m][n][2] * SCALE, acc[m][n][3] * SCALE);
            }
        }
}

// ---- att GEMMs: g0 att_p=ph@Hb (mask pm), g1 att_h=hp@P (mask hm), g2 self_p, g3 self_h
__global__ __launch_bounds__(256)
void mfma_att_k(const float* __restrict__ ph, const float* __restrict__ hp,
                const float* __restrict__ spA, const float* __restrict__ shA,
                const ushort* __restrict__ PbT, const ushort* __restrict__ HbT,
                const int* __restrict__ pma, const int* __restrict__ hma,
                ushort* __restrict__ attAb, ushort* __restrict__ selfAb) {
    __shared__ __align__(16) ushort As[128][32];
    __shared__ __align__(16) ushort Bs[128][32];
    int orig = swz_orig_3d();                 // grid (8,2,128)
    const int x = orig & 7; orig >>= 3;
    const int y = orig & 1; orig >>= 1;
    const int g = orig >> 5, b = orig & 31;
    const float*  W  = (g == 0 ? ph : g == 1 ? hp : g == 2 ? spA : shA) + (size_t)b * SS * SS;
    const ushort* BT = ((g == 0 || g == 3) ? HbT : PbT) + (size_t)b * DD * SS;
    const int* rmask = g == 0 ? pma + b * SS : g == 1 ? hma + b * SS : nullptr;
    const int side = (g == 1 || g == 3);
    ushort* Ob = (g < 2 ? attAb : selfAb) + ((size_t)side * NROW + (size_t)b * SS) * DD;
    const int col0 = x * 128, row0 = y * 128;
    MFMA_PREAMBLE();
    for (int k0 = 0; k0 < SS; k0 += 32) {
        bf16x8 ar[2], br[2];
#pragma unroll
        for (int i = 0; i < 2; ++i) {
            const int cid = tid + i * 256, srow = cid >> 2, skc = (cid & 3) * 8;
            ar[i] = ldf8(&W[(size_t)(row0 + srow) * SS + k0 + skc]);
            br[i] = *(const bf16x8*)&BT[(size_t)(col0 + srow) * SS + k0 + skc];
        }
        __syncthreads();
#pragma unroll
        for (int i = 0; i < 2; ++i) {
            const int cid = tid + i * 256, srow = cid >> 2, skc = (cid & 3) * 8;
            *(bf16x8*)&As[srow][skc] = ar[i];
            *(bf16x8*)&Bs[srow][skc] = br[i];
        }
        __syncthreads();
        MFMA_CORE();
    }
#pragma unroll
    for (int m = 0; m < 4; ++m)
#pragma unroll
        for (int n = 0; n < 4; ++n) {
            const int c = col0 + wc + n * 16 + fr;
#pragma unroll
            for (int r = 0; r < 4; ++r) {
                const int rr = row0 + wr + m * 16 + rq + r;
                const float mm = rmask ? (float)rmask[rr] : 1.0f;
                Ob[(size_t)rr * DD + c] = f2b(acc[m][n][r] * mm);
            }
        }
}

// ---- fuse: catb[row, kf*256+e]; rows 0..16383; X read from f32 P/H ----
__global__ __launch_bounds__(256)
void mfma_fuse_k(const float* __restrict__ P, const float* __restrict__ H,
                 const float* __restrict__ impS, const float* __restrict__ impI,
                 const ushort* __restrict__ W8T, const float* __restrict__ B8v,
                 ushort* __restrict__ catb) {
    __shared__ __align__(16) ushort As[128][32];
    __shared__ __align__(16) ushort Bs[128][32];
    const int orig = swz_orig_2d();           // grid (16,128)
    const int cb = orig & 15, rb = orig >> 4;
    const int kf = cb >> 1, e0 = (cb & 1) * 128, row0 = rb * 128;
    const float* X = (row0 < NROW) ? P : H;
    const int rbase = (row0 < NROW) ? row0 : row0 - NROW;
    MFMA_PREAMBLE();
    const ushort* Wk = W8T + (size_t)kf * EE * DD;

    int srow_[2]; float sA[2], iA[2], cf[2];
#pragma unroll
    for (int i = 0; i < 2; ++i) {
        const int cid = tid + i * 256;
        srow_[i] = cid >> 2;
        const int row = row0 + srow_[i];
        const float s_ = impS[row], i_ = impI[row];
        sA[i] = s_; iA[i] = i_;
        float c = 0.f;
        switch (kf) {
            case 0: c = s_ * i_;             break;
            case 1: c = s_ + i_;             break;
            case 2: c = fmaxf(s_, i_);       break;
            case 4: c = s_ * i_ + 1.f;       break;
            case 5: c = s_ + i_ + 1.f;       break;
            case 6: c = fmaxf(s_, i_) + 1.f; break;
            default: break;
        }
        cf[i] = c;
    }
    for (int k0 = 0; k0 < DD; k0 += 32) {
        bf16x8 ar[2], br[2];
#pragma unroll
        for (int i = 0; i < 2; ++i) {
            const int cid = tid + i * 256, skc = (cid & 3) * 8;
            const float* src = &X[(size_t)(rbase + srow_[i]) * DD + k0 + skc];
            const float4 u0 = ld4(src), u1 = ld4(src + 4);
            float v[8] = {u0.x, u0.y, u0.z, u0.w, u1.x, u1.y, u1.z, u1.w};
            if (kf == 3) {
#pragma unroll
                for (int j = 0; j < 8; ++j) v[j] = fmaxf(v[j] * sA[i], v[j] * iA[i]);
            } else if (kf == 7) {
#pragma unroll
                for (int j = 0; j < 8; ++j) v[j] = fmaxf(v[j] * sA[i], v[j] * iA[i]) + v[j];
            } else {
#pragma unroll
                for (int j = 0; j < 8; ++j) v[j] *= cf[i];
            }
            ar[i] = cvt8(v);
            br[i] = *(const bf16x8*)&Wk[(size_t)(e0 + srow_[i]) * DD + k0 + skc];
        }
        __syncthreads();
#pragma unroll
        for (int i = 0; i < 2; ++i) {
            const int cid = tid + i * 256, skc = (cid & 3) * 8;
            *(bf16x8*)&As[srow_[i]][skc] = ar[i];
            *(bf16x8*)&Bs[srow_[i]][skc] = br[i];
        }
        __syncthreads();
        MFMA_CORE();
    }
#pragma unroll
    for (int m = 0; m < 4; ++m)
#pragma unroll
        for (int n = 0; n < 4; ++n) {
            const int el = e0 + wc + n * 16 + fr;
            const float bv = B8v[kf * EE + el];
#pragma unroll
            for (int r = 0; r < 4; ++r) {
                const int rr = row0 + wr + m * 16 + rq + r;
                catb[(size_t)rr * FDIM + kf * EE + el] = f2b(acc[m][n][r] + bv);
            }
        }
}

// ---- lin: pall = relu(cat @ Wl + bl); rows 16384 ----
__global__ __launch_bounds__(256)
void mfma_lin_k(const ushort* __restrict__ A, const ushort* __restrict__ BT,
                const float* __restrict__ bias, ushort* __restrict__ C) {
    __shared__ __align__(16) ushort As[128][32];
    __shared__ __align__(16) ushort Bs[128][32];
    const int orig = swz_orig_2d();           // grid (16,128)
    const int col0 = (orig & 15) * 128, row0 = (orig >> 4) * 128;
    MFMA_PREAMBLE();
    for (int k0 = 0; k0 < FDIM; k0 += 32) {
        bf16x8 ar[2], br[2];
#pragma unroll
        for (int i = 0; i < 2; ++i) {
            const int cid = tid + i * 256, srow = cid >> 2, skc = (cid & 3) * 8;
            ar[i] = *(const bf16x8*)&A [(size_t)(row0 + srow) * FDIM + k0 + skc];
            br[i] = *(const bf16x8*)&BT[(size_t)(col0 + srow) * FDIM + k0 + skc];
        }
        __syncthreads();
#pragma unroll
        for (int i = 0; i < 2; ++i) {
            const int cid = tid + i * 256, srow = cid >> 2, skc = (cid & 3) * 8;
            *(bf16x8*)&As[srow][skc] = ar[i];
            *(bf16x8*)&Bs[srow][skc] = br[i];
        }
        __syncthreads();
        MFMA_CORE();
    }
#pragma unroll
    for (int m = 0; m < 4; ++m)
#pragma unroll
        for (int n = 0; n < 4; ++n) {
            const int c = col0 + wc + n * 16 + fr;
            const float bv = bias[c];
#pragma unroll
            for (int r = 0; r < 4; ++r) {
                const int rr = row0 + wr + m * 16 + rq + r;
                C[(size_t)rr * FDIM + c] = f2b(fmaxf(acc[m][n][r] + bv, 0.f));
            }
        }
}

// ---- out: relu(enh @ Wp + bp); rows 16384, writes d_out ----
__global__ __launch_bounds__(256)
void mfma_out_k(const float* __restrict__ P, const float* __restrict__ H,
                const ushort* __restrict__ attAb, const ushort* __restrict__ selfAb,
                const ushort* __restrict__ pallb, const ushort* __restrict__ WpT,
                const float* __restrict__ bp, float* __restrict__ out) {
    __shared__ __align__(16) ushort As[128][32];
    __shared__ __align__(16) ushort Bs[128][32];
    const int orig = swz_orig_2d();           // grid (4,128)
    const int col0 = (orig & 3) * 128, row0 = (orig >> 2) * 128;
    const float* Xb = (row0 < NROW) ? P : H;
    const int rX = (row0 < NROW) ? row0 : row0 - NROW;
    MFMA_PREAMBLE();
    for (int k0 = 0; k0 < KOUT; k0 += 32) {
        bf16x8 ar[2], br[2];
#pragma unroll
        for (int i = 0; i < 2; ++i) {
            const int cid = tid + i * 256, srow = cid >> 2, skc = (cid & 3) * 8;
            const int gr = row0 + srow;
            const int kg = k0 + skc;
            bf16x8 av;
            if (kg < DD) {
                av = ldf8(&Xb[(size_t)(rX + srow) * DD + kg]);
            } else if (kg < 2 * DD) {
                av = *(const bf16x8*)&attAb[(size_t)gr * DD + (kg - DD)];
            } else if (kg < 3 * DD) {
                av = *(const bf16x8*)&selfAb[(size_t)gr * DD + (kg - 2 * DD)];
            } else if (kg < 3 * DD + FDIM) {
                av = *(const bf16x8*)&pallb[(size_t)gr * FDIM + (kg - 3 * DD)];
            } else if (kg < 3 * DD + FDIM + DD) {
                const int d = kg - (3 * DD + FDIM);
                const float* xp = &Xb[(size_t)(rX + srow) * DD + d];
                const float4 x0 = ld4(xp), x1 = ld4(xp + 4);
                float tv[8];
                b2f8(*(const bf16x8*)&attAb[(size_t)gr * DD + d], tv);
                float v[8] = {x0.x * tv[0], x0.y * tv[1], x0.z * tv[2], x0.w * tv[3],
                              x1.x * tv[4], x1.y * tv[5], x1.z * tv[6], x1.w * tv[7]};
                av = cvt8(v);
            } else {
                const int d = kg - (3 * DD + FDIM + DD);
                const float* xp = &Xb[(size_t)(rX + srow) * DD + d];
                const float4 x0 = ld4(xp), x1 = ld4(xp + 4);
                float tv[8];
                b2f8(*(const bf16x8*)&attAb[(size_t)gr * DD + d], tv);
                float v[8] = {x0.x - tv[0], x0.y - tv[1], x0.z - tv[2], x0.w - tv[3],
                              x1.x - tv[4], x1.y - tv[5], x1.z - tv[6], x1.w - tv[7]};
                av = cvt8(v);
            }
            ar[i] = av;
            br[i] = *(const bf16x8*)&WpT[(size_t)(col0 + srow) * KOUT + kg];
        }
        __syncthreads();
#pragma unroll
        for (int i = 0; i < 2; ++i) {
            const int cid = tid + i * 256, srow = cid >> 2, skc = (cid & 3) * 8;
            *(bf16x8*)&As[srow][skc] = ar[i];
            *(bf16x8*)&Bs[srow][skc] = br[i];
        }
        __syncthreads();
        MFMA_CORE();
    }
#pragma unroll
    for (int m = 0; m < 4; ++m)
#pragma unroll
        for (int n = 0; n < 4; ++n) {
            const int c = col0 + wc + n * 16 + fr;
            const float bv = bp[c];
#pragma unroll
            for (int r = 0; r < 4; ++r) {
                const int rr = row0 + wr + m * 16 + rq + r;
                out[(size_t)rr * HH + c] = fmaxf(acc[m][n][r] + bv, 0.f);
            }
        }
}

// =========================== launcher ===========================
// Workspace budget (221.4 MB total, < 235 MB proven-safe in R1):
//   region0 (67.1 MB): [simPH|simPHT|simPP|simHH (33.5)][PbT|HbT (33.5)]
//                      -> aliased by catb (67.1) after mfma_att_k completes
//   impS/impI (0.13) | attAb/selfAb (67.1) | pallb (67.1) | WlT/WpT/W8T (19.9)
extern "C" void kernel_launch(void* const* d_in, const int* in_sizes, int n_in,
                              void* d_out, int out_size, void* d_ws, size_t ws_size,
                              hipStream_t stream) {
    const float* P   = (const float*)d_in[0];
    const float* Hb  = (const float*)d_in[1];
    const int*   pma = (const int*)d_in[2];
    const int*   hma = (const int*)d_in[3];
    const float* W8  = (const float*)d_in[4];
    const float* B8v = (const float*)d_in[5];
    const float* Wl  = (const float*)d_in[6];
    const float* bl  = (const float*)d_in[7];
    const float* Wp  = (const float*)d_in[8];
    const float* bp  = (const float*)d_in[9];

    char* base = (char*)d_ws;
    // region0 (aliased)
    float* simPH  = (float*)base;
    float* simPHT = simPH  + (size_t)BB * SS * SS;
    float* simPP  = simPHT + (size_t)BB * SS * SS;
    float* simHH  = simPP  + (size_t)BB * SS * SS;
    ushort* PbT   = (ushort*)(simHH + (size_t)BB * SS * SS);
    ushort* HbT   = PbT + (size_t)NROW * DD;
    ushort* catb  = (ushort*)base;                     // aliases all of region0
    char* cur = (char*)(HbT + (size_t)NROW * DD);
    auto alloc_f = [&](size_t n) { float*  p = (float*)cur;  cur += n * 4; return p; };
    auto alloc_u = [&](size_t n) { ushort* p = (ushort*)cur; cur += n * 2; return p; };
    float*  impS   = alloc_f(NROW2);
    float*  impI   = alloc_f(NROW2);
    ushort* attAb  = alloc_u((size_t)NROW2 * DD);
    ushort* selfAb = alloc_u((size_t)NROW2 * DD);
    ushort* pallb  = alloc_u((size_t)NROW2 * FDIM);
    ushort* WlT    = alloc_u((size_t)FDIM * FDIM);
    ushort* WpT    = alloc_u((size_t)HH * KOUT);
    ushort* W8T    = alloc_u((size_t)8 * EE * DD);

    float* outp = (float*)d_out;
    const dim3 blk(256);

    // ---- preps
    tpose_cvt_k<<<dim3(8, 32, BB), blk, 0, stream>>>(P,  PbT, SS, DD, (size_t)SS * DD, (size_t)DD * SS);
    tpose_cvt_k<<<dim3(8, 32, BB), blk, 0, stream>>>(Hb, HbT, SS, DD, (size_t)SS * DD, (size_t)DD * SS);
    tpose_cvt_k<<<dim3(FDIM / 32, FDIM / 32, 1), blk, 0, stream>>>(Wl, WlT, FDIM, FDIM, 0, 0);
    tpose_cvt_k<<<dim3(KOUT / 32, HH / 32, 1), blk, 0, stream>>>(Wp, WpT, KOUT, HH, 0, 0);
    tpose_cvt_k<<<dim3(DD / 32, EE / 32, 8), blk, 0, stream>>>(W8, W8T, DD, EE,
                                                               (size_t)DD * EE, (size_t)EE * DD);

    // ---- attention pipeline
    mfma_nt_k<<<dim3(2, 2, 96), blk, 0, stream>>>(P, Hb, simPH, simPHT, simPP, simHH);
    softmax4_k<<<dim3(NROW, 4), blk, 0, stream>>>(simPH, simPHT, simPP, simHH, pma, hma);
    colsum4_k<<<dim3(BB, 4), blk, 0, stream>>>(simPP, simHH, simPHT, simPH, impS, impI);
    mfma_att_k<<<dim3(8, 2, 128), blk, 0, stream>>>(simPH, simPHT, simPP, simHH, PbT, HbT,
                                                    pma, hma, attAb, selfAb);

    // ---- fused projection pipeline (both sides; catb aliases dead sim/PbT/HbT)
    mfma_fuse_k<<<dim3(16, 128), blk, 0, stream>>>(P, Hb, impS, impI, W8T, B8v, catb);
    mfma_lin_k<<<dim3(16, 128), blk, 0, stream>>>(catb, WlT, bl, pallb);
    mfma_out_k<<<dim3(4, 128), blk, 0, stream>>>(P, Hb, attAb, selfAb, pallb, WpT, bp, outp);

    (void)in_sizes; (void)n_in; (void)out_size; (void)ws_size;
}